// Round 4
// baseline (2000.717 us; speedup 1.0000x reference)
//
#include <hip/hip_runtime.h>
#include <hip/hip_bf16.h>

// MarioDoomPolicyNet: conv stack (4x stride-2 + ELU) -> 2-layer LSTM scan -> heads.
// R6: full conv fusion; transposed GEMM; merged heads. 2007.3 us.
// R7 FAILED: 1024-thr block caps VGPR at 128 (4 waves/SIMD, pool 512); w[256] spilled.
// R8: hybrid-resident scan (16 reg quads + 9 LDS quads + 39 streamed). 1812.6 us.
//     Counters now: k_convall 634us top, VALUBusy 78%, HBM 2% -> pure VALU-issue-bound.
// R9: convall VALU diet. (1) Stages D/E were 36/64 and 9/64 lanes (o-per-wave for
//     s_load weights): repack to 288 dense threads w/ per-lane o, weights via
//     global dwordx4 (L1-hit; VMEM pipe is idle anyway). Issue D 18.4k->10.4k,
//     E 18.4k->3k cyc/block. (2) libm expf (~20 inst) -> __expf (2 inst) in ELU
//     (19.4k/img) and scan sigm/tanh (per-step serial chain).
// R10: R9 bench timed out at GPU acquisition (never ran) — resubmitted unchanged.
// All f32 (precision requirement established R1/R2: argmax needs exact-ish logits).

#define T_ 64
#define B_ 64
#define NTB 4096
#define HID 256
#define G4 1024

typedef float f4 __attribute__((ext_vector_type(4)));

// XOR swizzle for LDS float4 slot j -> float column index (injective, 16B aligned)
#define XS(j) ((((j) << 2)) ^ ((((j) >> 3) & 7) << 2))

__device__ inline float sigm(float x) { return 1.f / (1.f + __expf(-x)); }
__device__ inline float tanh_(float x) { return 1.f - 2.f / (1.f + __expf(2.f * x)); }
__device__ inline float elu_(float x) { return x > 0.f ? x : __expf(x) - 1.f; }

// ---------------- prep: weight relayouts (all f32) ----------------
__global__ void k_prep(const float* __restrict__ wih0, const float* __restrict__ wih1,
                       const float* __restrict__ whh0, const float* __restrict__ whh1,
                       const float* __restrict__ cw2, const float* __restrict__ cw3,
                       const float* __restrict__ cw4, const float* __restrict__ pw,
                       const float* __restrict__ bw,
                       float* __restrict__ wih0T, float* __restrict__ wih1T,
                       float* __restrict__ wq0, float* __restrict__ wq1,
                       float* __restrict__ wc2, float* __restrict__ wc3,
                       float* __restrict__ wc4, float* __restrict__ pwT) {
  int idx = blockIdx.x * 256 + threadIdx.x;
  if (idx < 294912) {                       // wih0T[k*1024+j] = wih0[j*288+k]
    int k = idx >> 10, j = idx & 1023;
    wih0T[idx] = wih0[j * 288 + k];
  } else if (idx < 557056) {                // wih1T[k*1024+j] = wih1[j*256+k]
    int r = idx - 294912; int k = r >> 10, j = r & 1023;
    wih1T[r] = wih1[j * 256 + k];
  } else if (idx < 819200) {                // wq0[(k4*1024+row)*4+c] = whh0[row][4k4+c]
    int r = idx - 557056;
    int cc = r & 3, row = (r >> 2) & 1023, k4 = r >> 12;
    wq0[r] = whh0[row * 256 + k4 * 4 + cc];
  } else if (idx < 1081344) {
    int r = idx - 819200;
    int cc = r & 3, row = (r >> 2) & 1023, k4 = r >> 12;
    wq1[r] = whh1[row * 256 + k4 * 4 + cc];
  } else if (idx < 1108992) {               // conv weights -> [o][tap][i] f32
    int r = idx - 1081344;                  // 3 * 9216
    int which = r / 9216; int d = r - which * 9216;
    int i = d & 31, tap = (d >> 5) % 9, o = d / 288;
    int kh = tap / 3, kw = tap - kh * 3;
    const float* src = which == 0 ? cw2 : (which == 1 ? cw3 : cw4);
    float* dst = which == 0 ? wc2 : (which == 1 ? wc3 : wc4);
    dst[d] = src[((o * 32 + i) * 3 + kh) * 3 + kw];
  } else if (idx < 1113088) {               // pwT[k*16+o]: policy rows 0..11, baseline row 12
    int r = idx - 1108992; int k = r >> 4, o = r & 15;
    pwT[r] = o < 12 ? pw[o * 256 + k] : (o == 12 ? bw[k] : 0.f);
  }
}

// ---------------- done -> notdone float, robust to encoding (verified) ----------------
__global__ __launch_bounds__(1024)
void k_donecvt(const unsigned char* __restrict__ db, float* __restrict__ nd) {
  int tid = threadIdx.x;
  const unsigned* dw = (const unsigned*)db;
  unsigned w = dw[tid];
  int odd = ((w & 0xFFFFFF00u) != 0u && w != 0x3F800000u) ? 1 : 0;
  int any = __syncthreads_count(odd);
  bool u8 = (any > 0);
  for (int j = tid; j < 4096; j += 1024) {
    unsigned v = u8 ? (unsigned)db[j] : dw[j];
    nd[j] = v ? 0.f : 1.f;
  }
}

// ---------------- FUSED conv1..conv4: frame[n] -> featT[k][n] ----------------
// NCHW view: x[n][c][A][B] = frame[n][B][A][c].  All intermediates in LDS.
// LDS: a1t 8x1792 (57344B) + act2l 8x512 (16384B) + act3l 8x192 (6144B) = 79872B -> 2 blk/CU
__global__ __launch_bounds__(512)
void k_convall(const float* __restrict__ frame, const float* __restrict__ cw1,
               const float* __restrict__ cb1, const float* __restrict__ wc2,
               const float* __restrict__ cb2, const float* __restrict__ wc3,
               const float* __restrict__ cb3, const float* __restrict__ wc4,
               const float* __restrict__ cb4, float* __restrict__ featT) {
  __shared__ __align__(16) float a1t[8][1792];   // conv1 out: [oq][swizzled 441 pos x4]
  __shared__ __align__(16) float act2l[8][512];  // conv2 out: [oq][swizzled 121 pos x4]
  __shared__ __align__(16) float act3l[8][192];  // conv3 out: [oq][swizzled 36 pos x4]
  int n = blockIdx.x;
  int tid = threadIdx.x;
  const float4* fp = (const float4*)(frame + (size_t)n * 7056);

  // ---- stage B: conv1 (frame direct from global, L1-cached 9x reuse) ----
  if (tid < 441) {
    int p = tid / 21, q = tid - (tid / 21) * 21;
    float px[9][4];
#pragma unroll
    for (int kh = 0; kh < 3; ++kh) {
#pragma unroll
      for (int kw = 0; kw < 3; ++kw) {
        int A = 2 * p - 1 + kh, Bc = 2 * q - 1 + kw;
        bool ok = ((unsigned)A < 42u) && ((unsigned)Bc < 42u);
        float4 v = ok ? fp[Bc * 42 + A] : make_float4(0.f, 0.f, 0.f, 0.f);
        px[kh * 3 + kw][0] = v.x; px[kh * 3 + kw][1] = v.y;
        px[kh * 3 + kw][2] = v.z; px[kh * 3 + kw][3] = v.w;
      }
    }
    int col = XS(tid);
#pragma unroll
    for (int oq = 0; oq < 8; ++oq) {
      float4 acc;
      float* ap = (float*)&acc;
#pragma unroll
      for (int j = 0; j < 4; ++j) {
        int o = oq * 4 + j;
        float a = cb1[o];
        const float* w = cw1 + o * 36;           // [c][kh][kw], scalar s_load
#pragma unroll
        for (int tap = 0; tap < 9; ++tap)
          a += px[tap][0] * w[tap] + px[tap][1] * w[9 + tap] +
               px[tap][2] * w[18 + tap] + px[tap][3] * w[27 + tap];
        ap[j] = elu_(a);
      }
      *(float4*)&a1t[oq][col] = acc;
    }
  }
  __syncthreads();

  // ---- stage C: conv2 (21x21x32 -> 11x11x32), thread = (pos, o-octet) ----
  {
    int s = tid & 127, oh = tid >> 7;            // oh 0..3, wave-uniform
    int ob = __builtin_amdgcn_readfirstlane(oh << 3);
    if (s < 121) {
      int p = s / 11, q = s - (s / 11) * 11;
      float acc[8];
#pragma unroll
      for (int oi = 0; oi < 8; ++oi) acc[oi] = cb2[ob + oi];
#pragma unroll
      for (int kh = 0; kh < 3; ++kh) {
        int A = 2 * p - 1 + kh;
        if ((unsigned)A >= 21u) continue;
#pragma unroll
        for (int kw = 0; kw < 3; ++kw) {
          int Bc = 2 * q - 1 + kw;
          if ((unsigned)Bc >= 21u) continue;
          int pos = A * 21 + Bc;
          int col = XS(pos);
          int tap = kh * 3 + kw;
#pragma unroll
          for (int i4 = 0; i4 < 8; ++i4) {
            float4 v = *(const float4*)&a1t[i4][col];
#pragma unroll
            for (int oi = 0; oi < 8; ++oi) {
              const float* w = wc2 + ((ob + oi) * 9 + tap) * 32 + i4 * 4;  // s_load
              acc[oi] += v.x * w[0] + v.y * w[1] + v.z * w[2] + v.w * w[3];
            }
          }
        }
      }
      int colw = XS(s);
#pragma unroll
      for (int half = 0; half < 2; ++half) {
        float4 o4 = make_float4(elu_(acc[half * 4 + 0]), elu_(acc[half * 4 + 1]),
                                elu_(acc[half * 4 + 2]), elu_(acc[half * 4 + 3]));
        *(float4*)&act2l[(ob >> 2) + half][colw] = o4;
      }
    }
  }
  __syncthreads();

  // ---- stage D: conv3 (11x11x32 -> 6x6x32), 288 dense threads: oq=tid/36, pos=tid%36 ----
  // (R9: was 8 waves x 36 lanes = 56% util; per-lane o costs VMEM weight loads (L1-hit)
  //  but cuts wave-issue 18.4k -> 10.4k cyc/block)
  if (tid < 288) {
    int oq = tid / 36, s = tid - oq * 36;
    int p = s / 6, q = s - (s / 6) * 6;
    float acc[4];
#pragma unroll
    for (int j = 0; j < 4; ++j) acc[j] = cb3[oq * 4 + j];
#pragma unroll
    for (int kh = 0; kh < 3; ++kh) {
      int A = 2 * p - 1 + kh;
      if ((unsigned)A >= 11u) continue;
#pragma unroll
      for (int kw = 0; kw < 3; ++kw) {
        int Bc = 2 * q - 1 + kw;
        if ((unsigned)Bc >= 11u) continue;
        int col = XS(A * 11 + Bc);
        int tap = kh * 3 + kw;
#pragma unroll
        for (int i4 = 0; i4 < 8; ++i4) {
          float4 v = *(const float4*)&act2l[i4][col];
#pragma unroll
          for (int j = 0; j < 4; ++j) {
            float4 w4 = *(const float4*)(wc3 + (((oq * 4 + j) * 9 + tap) << 5) + (i4 << 2));
            acc[j] += v.x * w4.x + v.y * w4.y + v.z * w4.z + v.w * w4.w;
          }
        }
      }
    }
    float4 o4 = make_float4(elu_(acc[0]), elu_(acc[1]), elu_(acc[2]), elu_(acc[3]));
    *(float4*)&act3l[oq][XS(s)] = o4;
  }
  __syncthreads();

  // ---- stage E: conv4 (6x6x32 -> 3x3x32), 288 dense threads: o=tid/9, pos=tid%9 ----
  // (R9: was 8 waves x 9 lanes = 14% util -> 4.5 waves x 100%; issue 18.4k -> ~3k)
  if (tid < 288) {
    int o = tid / 9, s = tid - o * 9;
    int p = s / 3, q = s - (s / 3) * 3;
    float acc = cb4[o];
#pragma unroll
    for (int kh = 0; kh < 3; ++kh) {
      int A = 2 * p - 1 + kh;
      if ((unsigned)A >= 6u) continue;
#pragma unroll
      for (int kw = 0; kw < 3; ++kw) {
        int Bc = 2 * q - 1 + kw;
        if ((unsigned)Bc >= 6u) continue;
        int col = XS(A * 6 + Bc);
        int tap = kh * 3 + kw;
#pragma unroll
        for (int i4 = 0; i4 < 8; ++i4) {
          float4 v = *(const float4*)&act3l[i4][col];
          float4 w4 = *(const float4*)(wc4 + ((o * 9 + tap) << 5) + (i4 << 2));
          acc += v.x * w4.x + v.y * w4.y + v.z * w4.z + v.w * w4.w;
        }
      }
    }
    featT[(size_t)(o * 9 + s) * 4096 + n] = elu_(acc);  // feat k = c*9 + p*3 + q
  }
}

// ---------------- GEMM on transposed input: out[n][j] = sum_k inT[k][n]*wT[k][j] + b ----
// lane = n (coalesced vector load), wave-uniform 16-float weight chunk (s_load), 16 FMA/k.
__global__ __launch_bounds__(256)
void k_gemm2(const float* __restrict__ inT, const float* __restrict__ wT,
             const float* __restrict__ b1, const float* __restrict__ b2,
             float* __restrict__ out, int K) {
  int nb = blockIdx.x >> 4, jb = blockIdx.x & 15;
  int lane = threadIdx.x & 63, wv = threadIdx.x >> 6;
  int n = nb * 64 + lane;
  int j0 = jb * 64 + __builtin_amdgcn_readfirstlane(wv << 4);
  float acc[16];
#pragma unroll
  for (int m = 0; m < 16; ++m) acc[m] = 0.f;
  const float* ip = inT + n;
#pragma unroll 4
  for (int k = 0; k < K; ++k) {
    float x = ip[(size_t)k * 4096];
    const float* w = wT + k * 1024 + j0;         // wave-uniform -> s_load x16
#pragma unroll
    for (int m = 0; m < 16; ++m) acc[m] += x * w[m];
  }
  float* op = out + (size_t)n * 1024 + j0;
#pragma unroll
  for (int h = 0; h < 4; ++h) {
    float4 o4 = make_float4(acc[h * 4 + 0] + b1[j0 + h * 4 + 0] + b2[j0 + h * 4 + 0],
                            acc[h * 4 + 1] + b1[j0 + h * 4 + 1] + b2[j0 + h * 4 + 1],
                            acc[h * 4 + 2] + b1[j0 + h * 4 + 2] + b2[j0 + h * 4 + 2],
                            acc[h * 4 + 3] + b1[j0 + h * 4 + 3] + b2[j0 + h * 4 + 3]);
    *(float4*)&op[h * 4] = o4;
  }
}

// ---------------- LSTM scan (one layer): 64 WGs, 1 batch elem each ----------------
// R8 hybrid-resident: thread j owns gate row j. Row's 64 weight quads split:
//   k4  0..15 -> 16 NAMED f4 register vars (64 VGPR, under the 128 cap @16 waves)
//   k4 16..24 -> LDS wl[9][1024] (147KB; 1 blk/CU)
//   k4 25..63 -> streamed from L2 each step (639KB/step, per-CU-port bound)
// h broadcast via uniform ds_read_b128. R9: fast sigm/tanh (__expf) on the
// per-step serial chain.
#define WREGS(X) X(0) X(1) X(2) X(3) X(4) X(5) X(6) X(7) \
                 X(8) X(9) X(10) X(11) X(12) X(13) X(14) X(15)

__global__ __launch_bounds__(1024, 4)
void k_scan(const float* __restrict__ wq, const float* __restrict__ G,
            const float* __restrict__ h_init, const float* __restrict__ c_init,
            const float* __restrict__ ndb, float* __restrict__ h_allT,
            float* __restrict__ hT, float* __restrict__ cT) {
  int b = blockIdx.x, j = threadIdx.x;
  __shared__ __align__(16) float hs[256];
  __shared__ __align__(16) f4 wl[9][1024];       // 147456 B
  __shared__ float gl[1024];
  const f4* wq4 = (const f4*)wq;                 // wq4[k4*1024 + row] = whh[row][4k4..]
  // resident register quads k4 = 0..15 (named vars: nothing for SROA to spill)
#define DECLR(i) f4 wr##i = wq4[(i) * 1024 + j];
  WREGS(DECLR)
#undef DECLR
  // LDS-resident quads k4 = 16..24
#pragma unroll
  for (int q = 0; q < 9; ++q) wl[q][j] = wq4[(16 + q) * 1024 + j];
  float c = 0.f;
  if (j < 256) { hs[j] = h_init[b * HID + j]; c = c_init[b * HID + j]; }
  __syncthreads();
  const f4* hs4 = (const f4*)hs;
  const f4* sp = wq4 + 25 * 1024 + j;            // streamed quads k4 = 25..63
  const float* gp = G + b * G4 + j;
  float hlast = 0.f;
  for (int t = 0; t < T_; ++t) {
    float nd = ndb[t * B_ + b];
    f4 acc = {0.f, 0.f, 0.f, 0.f};
#define FMAR(i) { f4 h4 = hs4[i]; acc += h4 * wr##i; }
    WREGS(FMAR)
#undef FMAR
#pragma unroll
    for (int q = 0; q < 9; ++q) { f4 h4 = hs4[16 + q]; acc += h4 * wl[q][j]; }
#pragma unroll 4
    for (int q = 0; q < 39; ++q) { f4 h4 = hs4[25 + q]; acc += h4 * sp[(size_t)q * 1024]; }
    float g = gp[(size_t)t * (B_ * G4)] + (acc.x + acc.y + acc.z + acc.w) * nd;
    gl[j] = g;
    __syncthreads();                             // gates ready
    if (j < 256) {
      float gi = gl[j], gf = gl[j + 256], gg = gl[j + 512], go = gl[j + 768];
      c = sigm(gf) * (c * nd) + sigm(gi) * tanh_(gg);
      float h = sigm(go) * tanh_(c);
      hs[j] = h;
      h_allT[(size_t)j * 4096 + t * B_ + b] = h;
      hlast = h;
    }
    __syncthreads();                             // hs updated before next step
  }
  if (j < 256) { hT[b * HID + j] = hlast; cT[b * HID + j] = c; }
}

// ---------------- heads + argmax (merged): thread = n, reads h1aT coalesced ----------
__global__ __launch_bounds__(256)
void k_heads(const float* __restrict__ h1aT, const float* __restrict__ pwT,
             const float* __restrict__ pb, const float* __restrict__ bb,
             float* __restrict__ out) {
  int n = blockIdx.x * 256 + threadIdx.x;
  float acc[13];
#pragma unroll
  for (int o = 0; o < 12; ++o) acc[o] = pb[o];
  acc[12] = bb[0];
  for (int k = 0; k < 256; ++k) {
    float h = h1aT[(size_t)k * 4096 + n];
    const float* w = pwT + k * 16;               // uniform -> s_load
#pragma unroll
    for (int o = 0; o < 13; ++o) acc[o] += h * w[o];
  }
  float best = acc[0]; int bi = 0;
#pragma unroll
  for (int o = 1; o < 12; ++o)
    if (acc[o] > best) { best = acc[o]; bi = o; }   // strict > == first-max-wins
#pragma unroll
  for (int o = 0; o < 12; ++o) out[n * 12 + o] = acc[o];
  out[49152 + n] = acc[12];
  out[53248 + n] = (float)bi;
}

extern "C" void kernel_launch(void* const* d_in, const int* in_sizes, int n_in,
                              void* d_out, int out_size, void* d_ws, size_t ws_size,
                              hipStream_t stream) {
  const float* frame = (const float*)d_in[0];
  const unsigned char* done = (const unsigned char*)d_in[1];
  const float* h0 = (const float*)d_in[2];
  const float* c0 = (const float*)d_in[3];
  const float* cw1 = (const float*)d_in[4];  const float* cb1 = (const float*)d_in[5];
  const float* cw2 = (const float*)d_in[6];  const float* cb2 = (const float*)d_in[7];
  const float* cw3 = (const float*)d_in[8];  const float* cb3 = (const float*)d_in[9];
  const float* cw4 = (const float*)d_in[10]; const float* cb4 = (const float*)d_in[11];
  const float* wih0 = (const float*)d_in[12]; const float* whh0 = (const float*)d_in[13];
  const float* bih0 = (const float*)d_in[14]; const float* bhh0 = (const float*)d_in[15];
  const float* wih1 = (const float*)d_in[16]; const float* whh1 = (const float*)d_in[17];
  const float* bih1 = (const float*)d_in[18]; const float* bhh1 = (const float*)d_in[19];
  const float* pw = (const float*)d_in[20]; const float* pb = (const float*)d_in[21];
  const float* bw = (const float*)d_in[22]; const float* bb = (const float*)d_in[23];

  // workspace layout (~51 MB, all f32)
  float* featT = (float*)d_ws;                      //  1,179,648  [288][4096]
  float* G0    = featT + 1179648;                   //  4,194,304
  float* G1    = G0 + 4194304;                      //  4,194,304
  float* h0aT  = G1 + 4194304;                      //  1,048,576  [256][4096]
  float* h1aT  = h0aT + 1048576;                    //  1,048,576
  float* wih0T = h1aT + 1048576;                    //    294,912
  float* wih1T = wih0T + 294912;                    //    262,144
  float* wq0   = wih1T + 262144;                    //    262,144  whh0 quad layout
  float* wq1   = wq0 + 262144;                      //    262,144  whh1 quad layout
  float* wc2   = wq1 + 262144;                      //      9,216
  float* wc3   = wc2 + 9216;
  float* wc4   = wc3 + 9216;
  float* pwT   = wc4 + 9216;                        //      4,096
  float* ndb   = pwT + 4096;                        //      4,096

  float* out = (float*)d_out;
  float* o_hT = out + 57344;
  float* o_cT = out + 90112;

  k_prep<<<4348, 256, 0, stream>>>(wih0, wih1, whh0, whh1, cw2, cw3, cw4, pw, bw,
                                   wih0T, wih1T, wq0, wq1, wc2, wc3, wc4, pwT);
  k_donecvt<<<1, 1024, 0, stream>>>(done, ndb);
  k_convall<<<4096, 512, 0, stream>>>(frame, cw1, cb1, wc2, cb2, wc3, cb3, wc4, cb4,
                                      featT);
  k_gemm2<<<1024, 256, 0, stream>>>(featT, wih0T, bih0, bhh0, G0, 288);
  k_scan<<<64, 1024, 0, stream>>>(wq0, G0, h0, c0, ndb, h0aT, o_hT, o_cT);
  k_gemm2<<<1024, 256, 0, stream>>>(h0aT, wih1T, bih1, bhh1, G1, 256);
  k_scan<<<64, 1024, 0, stream>>>(wq1, G1, h0 + 16384, c0 + 16384, ndb, h1aT,
                                  o_hT + 16384, o_cT + 16384);
  k_heads<<<16, 256, 0, stream>>>(h1aT, pwT, pb, bb, out);
}

// Round 6
// 1706.531 us; speedup vs baseline: 1.1724x; 1.1724x over previous
//
#include <hip/hip_runtime.h>
#include <hip/hip_bf16.h>

// MarioDoomPolicyNet: conv stack (4x stride-2 + ELU) -> 2-layer LSTM scan -> heads.
// R6: full conv fusion; transposed GEMM; merged heads. 2007.3 us.
// R7 FAILED: 1024-thr block caps VGPR at 128 (4 waves/SIMD, pool 512); w[256] spilled.
// R8: hybrid-resident scan (16 reg quads + 9 LDS quads + 39 streamed). 1812.6 us.
// R9/R10 REGRESSED (2000.7): D/E per-lane VMEM weights pushed VGPR 52->68, crossing
//     the 64-VGPR occupancy step (m69): 2 blk/CU -> 1, occ 46->23%, convall 634->878.
//     __expf exonerated (absmax tightened to 0.0039). Lesson: VGPR<=64 is the binding
//     constraint for convall, not wave-issue density.
// R11: revert D/E to R8 o-per-wave s_load structure; pin __launch_bounds__(512,8)
//     (VGPR cap 64 — R8 achieved 52 naturally); keep __expf (ELU + scan gates).
// R12: R11 bench timed out at GPU acquisition (never ran) — resubmitted unchanged.
// All f32 (precision requirement established R1/R2: argmax needs exact-ish logits).

#define T_ 64
#define B_ 64
#define NTB 4096
#define HID 256
#define G4 1024

typedef float f4 __attribute__((ext_vector_type(4)));

// XOR swizzle for LDS float4 slot j -> float column index (injective, 16B aligned)
#define XS(j) ((((j) << 2)) ^ ((((j) >> 3) & 7) << 2))

__device__ inline float sigm(float x) { return 1.f / (1.f + __expf(-x)); }
__device__ inline float tanh_(float x) { return 1.f - 2.f / (1.f + __expf(2.f * x)); }
__device__ inline float elu_(float x) { return x > 0.f ? x : __expf(x) - 1.f; }

// ---------------- prep: weight relayouts (all f32) ----------------
__global__ void k_prep(const float* __restrict__ wih0, const float* __restrict__ wih1,
                       const float* __restrict__ whh0, const float* __restrict__ whh1,
                       const float* __restrict__ cw2, const float* __restrict__ cw3,
                       const float* __restrict__ cw4, const float* __restrict__ pw,
                       const float* __restrict__ bw,
                       float* __restrict__ wih0T, float* __restrict__ wih1T,
                       float* __restrict__ wq0, float* __restrict__ wq1,
                       float* __restrict__ wc2, float* __restrict__ wc3,
                       float* __restrict__ wc4, float* __restrict__ pwT) {
  int idx = blockIdx.x * 256 + threadIdx.x;
  if (idx < 294912) {                       // wih0T[k*1024+j] = wih0[j*288+k]
    int k = idx >> 10, j = idx & 1023;
    wih0T[idx] = wih0[j * 288 + k];
  } else if (idx < 557056) {                // wih1T[k*1024+j] = wih1[j*256+k]
    int r = idx - 294912; int k = r >> 10, j = r & 1023;
    wih1T[r] = wih1[j * 256 + k];
  } else if (idx < 819200) {                // wq0[(k4*1024+row)*4+c] = whh0[row][4k4+c]
    int r = idx - 557056;
    int cc = r & 3, row = (r >> 2) & 1023, k4 = r >> 12;
    wq0[r] = whh0[row * 256 + k4 * 4 + cc];
  } else if (idx < 1081344) {
    int r = idx - 819200;
    int cc = r & 3, row = (r >> 2) & 1023, k4 = r >> 12;
    wq1[r] = whh1[row * 256 + k4 * 4 + cc];
  } else if (idx < 1108992) {               // conv weights -> [o][tap][i] f32
    int r = idx - 1081344;                  // 3 * 9216
    int which = r / 9216; int d = r - which * 9216;
    int i = d & 31, tap = (d >> 5) % 9, o = d / 288;
    int kh = tap / 3, kw = tap - kh * 3;
    const float* src = which == 0 ? cw2 : (which == 1 ? cw3 : cw4);
    float* dst = which == 0 ? wc2 : (which == 1 ? wc3 : wc4);
    dst[d] = src[((o * 32 + i) * 3 + kh) * 3 + kw];
  } else if (idx < 1113088) {               // pwT[k*16+o]: policy rows 0..11, baseline row 12
    int r = idx - 1108992; int k = r >> 4, o = r & 15;
    pwT[r] = o < 12 ? pw[o * 256 + k] : (o == 12 ? bw[k] : 0.f);
  }
}

// ---------------- done -> notdone float, robust to encoding (verified) ----------------
__global__ __launch_bounds__(1024)
void k_donecvt(const unsigned char* __restrict__ db, float* __restrict__ nd) {
  int tid = threadIdx.x;
  const unsigned* dw = (const unsigned*)db;
  unsigned w = dw[tid];
  int odd = ((w & 0xFFFFFF00u) != 0u && w != 0x3F800000u) ? 1 : 0;
  int any = __syncthreads_count(odd);
  bool u8 = (any > 0);
  for (int j = tid; j < 4096; j += 1024) {
    unsigned v = u8 ? (unsigned)db[j] : dw[j];
    nd[j] = v ? 0.f : 1.f;
  }
}

// ---------------- FUSED conv1..conv4: frame[n] -> featT[k][n] ----------------
// NCHW view: x[n][c][A][B] = frame[n][B][A][c].  All intermediates in LDS.
// LDS: a1t 8x1792 (57344B) + act2l 8x512 (16384B) + act3l 8x192 (6144B) = 79872B -> 2 blk/CU
// __launch_bounds__(512,8): min 8 waves/EU -> VGPR cap 64 (R8 structure compiled to 52;
// protects the 64-VGPR occupancy step found in R9/R10).
__global__ __launch_bounds__(512, 8)
void k_convall(const float* __restrict__ frame, const float* __restrict__ cw1,
               const float* __restrict__ cb1, const float* __restrict__ wc2,
               const float* __restrict__ cb2, const float* __restrict__ wc3,
               const float* __restrict__ cb3, const float* __restrict__ wc4,
               const float* __restrict__ cb4, float* __restrict__ featT) {
  __shared__ __align__(16) float a1t[8][1792];   // conv1 out: [oq][swizzled 441 pos x4]
  __shared__ __align__(16) float act2l[8][512];  // conv2 out: [oq][swizzled 121 pos x4]
  __shared__ __align__(16) float act3l[8][192];  // conv3 out: [oq][swizzled 36 pos x4]
  int n = blockIdx.x;
  int tid = threadIdx.x;
  const float4* fp = (const float4*)(frame + (size_t)n * 7056);

  // ---- stage B: conv1 (frame direct from global, L1-cached 9x reuse) ----
  if (tid < 441) {
    int p = tid / 21, q = tid - (tid / 21) * 21;
    float px[9][4];
#pragma unroll
    for (int kh = 0; kh < 3; ++kh) {
#pragma unroll
      for (int kw = 0; kw < 3; ++kw) {
        int A = 2 * p - 1 + kh, Bc = 2 * q - 1 + kw;
        bool ok = ((unsigned)A < 42u) && ((unsigned)Bc < 42u);
        float4 v = ok ? fp[Bc * 42 + A] : make_float4(0.f, 0.f, 0.f, 0.f);
        px[kh * 3 + kw][0] = v.x; px[kh * 3 + kw][1] = v.y;
        px[kh * 3 + kw][2] = v.z; px[kh * 3 + kw][3] = v.w;
      }
    }
    int col = XS(tid);
#pragma unroll
    for (int oq = 0; oq < 8; ++oq) {
      float4 acc;
      float* ap = (float*)&acc;
#pragma unroll
      for (int j = 0; j < 4; ++j) {
        int o = oq * 4 + j;
        float a = cb1[o];
        const float* w = cw1 + o * 36;           // [c][kh][kw], scalar s_load
#pragma unroll
        for (int tap = 0; tap < 9; ++tap)
          a += px[tap][0] * w[tap] + px[tap][1] * w[9 + tap] +
               px[tap][2] * w[18 + tap] + px[tap][3] * w[27 + tap];
        ap[j] = elu_(a);
      }
      *(float4*)&a1t[oq][col] = acc;
    }
  }
  __syncthreads();

  // ---- stage C: conv2 (21x21x32 -> 11x11x32), thread = (pos, o-octet) ----
  {
    int s = tid & 127, oh = tid >> 7;            // oh 0..3, wave-uniform
    int ob = __builtin_amdgcn_readfirstlane(oh << 3);
    if (s < 121) {
      int p = s / 11, q = s - (s / 11) * 11;
      float acc[8];
#pragma unroll
      for (int oi = 0; oi < 8; ++oi) acc[oi] = cb2[ob + oi];
#pragma unroll
      for (int kh = 0; kh < 3; ++kh) {
        int A = 2 * p - 1 + kh;
        if ((unsigned)A >= 21u) continue;
#pragma unroll
        for (int kw = 0; kw < 3; ++kw) {
          int Bc = 2 * q - 1 + kw;
          if ((unsigned)Bc >= 21u) continue;
          int pos = A * 21 + Bc;
          int col = XS(pos);
          int tap = kh * 3 + kw;
#pragma unroll
          for (int i4 = 0; i4 < 8; ++i4) {
            float4 v = *(const float4*)&a1t[i4][col];
#pragma unroll
            for (int oi = 0; oi < 8; ++oi) {
              const float* w = wc2 + ((ob + oi) * 9 + tap) * 32 + i4 * 4;  // s_load
              acc[oi] += v.x * w[0] + v.y * w[1] + v.z * w[2] + v.w * w[3];
            }
          }
        }
      }
      int colw = XS(s);
#pragma unroll
      for (int half = 0; half < 2; ++half) {
        float4 o4 = make_float4(elu_(acc[half * 4 + 0]), elu_(acc[half * 4 + 1]),
                                elu_(acc[half * 4 + 2]), elu_(acc[half * 4 + 3]));
        *(float4*)&act2l[(ob >> 2) + half][colw] = o4;
      }
    }
  }
  __syncthreads();

  // ---- stage D: conv3 (11x11x32 -> 6x6x32), wave = o-quad, lanes = 36 pos ----
  // (R11: reverted to R8 o-per-wave s_load form — low VGPR beats lane density here)
  {
    int wv = tid >> 6, lane = tid & 63;
    int oq = __builtin_amdgcn_readfirstlane(wv);
    if (lane < 36) {
      int p = lane / 6, q = lane - (lane / 6) * 6;
      float acc[4];
#pragma unroll
      for (int j = 0; j < 4; ++j) acc[j] = cb3[oq * 4 + j];
#pragma unroll
      for (int kh = 0; kh < 3; ++kh) {
        int A = 2 * p - 1 + kh;
        if ((unsigned)A >= 11u) continue;
#pragma unroll
        for (int kw = 0; kw < 3; ++kw) {
          int Bc = 2 * q - 1 + kw;
          if ((unsigned)Bc >= 11u) continue;
          int col = XS(A * 11 + Bc);
          int tap = kh * 3 + kw;
#pragma unroll
          for (int i4 = 0; i4 < 8; ++i4) {
            float4 v = *(const float4*)&act2l[i4][col];
#pragma unroll
            for (int j = 0; j < 4; ++j) {
              const float* w = wc3 + ((oq * 4 + j) * 9 + tap) * 32 + i4 * 4;  // s_load
              acc[j] += v.x * w[0] + v.y * w[1] + v.z * w[2] + v.w * w[3];
            }
          }
        }
      }
      float4 o4 = make_float4(elu_(acc[0]), elu_(acc[1]), elu_(acc[2]), elu_(acc[3]));
      *(float4*)&act3l[oq][XS(p * 6 + q)] = o4;
    }
  }
  __syncthreads();

  // ---- stage E: conv4 (6x6x32 -> 3x3x32), wave = o-quad, lanes = 9 pos; featT out ----
  {
    int wv = tid >> 6, lane = tid & 63;
    int oq = __builtin_amdgcn_readfirstlane(wv);
    if (lane < 9) {
      int p = lane / 3, q = lane - (lane / 3) * 3;
      float acc[4];
#pragma unroll
      for (int j = 0; j < 4; ++j) acc[j] = cb4[oq * 4 + j];
#pragma unroll
      for (int kh = 0; kh < 3; ++kh) {
        int A = 2 * p - 1 + kh;
        if ((unsigned)A >= 6u) continue;
#pragma unroll
        for (int kw = 0; kw < 3; ++kw) {
          int Bc = 2 * q - 1 + kw;
          if ((unsigned)Bc >= 6u) continue;
          int col = XS(A * 6 + Bc);
          int tap = kh * 3 + kw;
#pragma unroll
          for (int i4 = 0; i4 < 8; ++i4) {
            float4 v = *(const float4*)&act3l[i4][col];
#pragma unroll
            for (int j = 0; j < 4; ++j) {
              const float* w = wc4 + ((oq * 4 + j) * 9 + tap) * 32 + i4 * 4;  // s_load
              acc[j] += v.x * w[0] + v.y * w[1] + v.z * w[2] + v.w * w[3];
            }
          }
        }
      }
#pragma unroll
      for (int j = 0; j < 4; ++j)                // feat k = c*9 + p*3 + q
        featT[(size_t)((oq * 4 + j) * 9 + lane) * 4096 + n] = elu_(acc[j]);
    }
  }
}

// ---------------- GEMM on transposed input: out[n][j] = sum_k inT[k][n]*wT[k][j] + b ----
// lane = n (coalesced vector load), wave-uniform 16-float weight chunk (s_load), 16 FMA/k.
__global__ __launch_bounds__(256)
void k_gemm2(const float* __restrict__ inT, const float* __restrict__ wT,
             const float* __restrict__ b1, const float* __restrict__ b2,
             float* __restrict__ out, int K) {
  int nb = blockIdx.x >> 4, jb = blockIdx.x & 15;
  int lane = threadIdx.x & 63, wv = threadIdx.x >> 6;
  int n = nb * 64 + lane;
  int j0 = jb * 64 + __builtin_amdgcn_readfirstlane(wv << 4);
  float acc[16];
#pragma unroll
  for (int m = 0; m < 16; ++m) acc[m] = 0.f;
  const float* ip = inT + n;
#pragma unroll 4
  for (int k = 0; k < K; ++k) {
    float x = ip[(size_t)k * 4096];
    const float* w = wT + k * 1024 + j0;         // wave-uniform -> s_load x16
#pragma unroll
    for (int m = 0; m < 16; ++m) acc[m] += x * w[m];
  }
  float* op = out + (size_t)n * 1024 + j0;
#pragma unroll
  for (int h = 0; h < 4; ++h) {
    float4 o4 = make_float4(acc[h * 4 + 0] + b1[j0 + h * 4 + 0] + b2[j0 + h * 4 + 0],
                            acc[h * 4 + 1] + b1[j0 + h * 4 + 1] + b2[j0 + h * 4 + 1],
                            acc[h * 4 + 2] + b1[j0 + h * 4 + 2] + b2[j0 + h * 4 + 2],
                            acc[h * 4 + 3] + b1[j0 + h * 4 + 3] + b2[j0 + h * 4 + 3]);
    *(float4*)&op[h * 4] = o4;
  }
}

// ---------------- LSTM scan (one layer): 64 WGs, 1 batch elem each ----------------
// R8 hybrid-resident: thread j owns gate row j. Row's 64 weight quads split:
//   k4  0..15 -> 16 NAMED f4 register vars (64 VGPR, under the 128 cap @16 waves)
//   k4 16..24 -> LDS wl[9][1024] (147KB; 1 blk/CU)
//   k4 25..63 -> streamed from L2 each step (639KB/step, per-CU-port bound)
// h broadcast via uniform ds_read_b128. Fast sigm/tanh (__expf) on the serial chain.
#define WREGS(X) X(0) X(1) X(2) X(3) X(4) X(5) X(6) X(7) \
                 X(8) X(9) X(10) X(11) X(12) X(13) X(14) X(15)

__global__ __launch_bounds__(1024, 4)
void k_scan(const float* __restrict__ wq, const float* __restrict__ G,
            const float* __restrict__ h_init, const float* __restrict__ c_init,
            const float* __restrict__ ndb, float* __restrict__ h_allT,
            float* __restrict__ hT, float* __restrict__ cT) {
  int b = blockIdx.x, j = threadIdx.x;
  __shared__ __align__(16) float hs[256];
  __shared__ __align__(16) f4 wl[9][1024];       // 147456 B
  __shared__ float gl[1024];
  const f4* wq4 = (const f4*)wq;                 // wq4[k4*1024 + row] = whh[row][4k4..]
  // resident register quads k4 = 0..15 (named vars: nothing for SROA to spill)
#define DECLR(i) f4 wr##i = wq4[(i) * 1024 + j];
  WREGS(DECLR)
#undef DECLR
  // LDS-resident quads k4 = 16..24
#pragma unroll
  for (int q = 0; q < 9; ++q) wl[q][j] = wq4[(16 + q) * 1024 + j];
  float c = 0.f;
  if (j < 256) { hs[j] = h_init[b * HID + j]; c = c_init[b * HID + j]; }
  __syncthreads();
  const f4* hs4 = (const f4*)hs;
  const f4* sp = wq4 + 25 * 1024 + j;            // streamed quads k4 = 25..63
  const float* gp = G + b * G4 + j;
  float hlast = 0.f;
  for (int t = 0; t < T_; ++t) {
    float nd = ndb[t * B_ + b];
    f4 acc = {0.f, 0.f, 0.f, 0.f};
#define FMAR(i) { f4 h4 = hs4[i]; acc += h4 * wr##i; }
    WREGS(FMAR)
#undef FMAR
#pragma unroll
    for (int q = 0; q < 9; ++q) { f4 h4 = hs4[16 + q]; acc += h4 * wl[q][j]; }
#pragma unroll 4
    for (int q = 0; q < 39; ++q) { f4 h4 = hs4[25 + q]; acc += h4 * sp[(size_t)q * 1024]; }
    float g = gp[(size_t)t * (B_ * G4)] + (acc.x + acc.y + acc.z + acc.w) * nd;
    gl[j] = g;
    __syncthreads();                             // gates ready
    if (j < 256) {
      float gi = gl[j], gf = gl[j + 256], gg = gl[j + 512], go = gl[j + 768];
      c = sigm(gf) * (c * nd) + sigm(gi) * tanh_(gg);
      float h = sigm(go) * tanh_(c);
      hs[j] = h;
      h_allT[(size_t)j * 4096 + t * B_ + b] = h;
      hlast = h;
    }
    __syncthreads();                             // hs updated before next step
  }
  if (j < 256) { hT[b * HID + j] = hlast; cT[b * HID + j] = c; }
}

// ---------------- heads + argmax (merged): thread = n, reads h1aT coalesced ----------
__global__ __launch_bounds__(256)
void k_heads(const float* __restrict__ h1aT, const float* __restrict__ pwT,
             const float* __restrict__ pb, const float* __restrict__ bb,
             float* __restrict__ out) {
  int n = blockIdx.x * 256 + threadIdx.x;
  float acc[13];
#pragma unroll
  for (int o = 0; o < 12; ++o) acc[o] = pb[o];
  acc[12] = bb[0];
  for (int k = 0; k < 256; ++k) {
    float h = h1aT[(size_t)k * 4096 + n];
    const float* w = pwT + k * 16;               // uniform -> s_load
#pragma unroll
    for (int o = 0; o < 13; ++o) acc[o] += h * w[o];
  }
  float best = acc[0]; int bi = 0;
#pragma unroll
  for (int o = 1; o < 12; ++o)
    if (acc[o] > best) { best = acc[o]; bi = o; }   // strict > == first-max-wins
#pragma unroll
  for (int o = 0; o < 12; ++o) out[n * 12 + o] = acc[o];
  out[49152 + n] = acc[12];
  out[53248 + n] = (float)bi;
}

extern "C" void kernel_launch(void* const* d_in, const int* in_sizes, int n_in,
                              void* d_out, int out_size, void* d_ws, size_t ws_size,
                              hipStream_t stream) {
  const float* frame = (const float*)d_in[0];
  const unsigned char* done = (const unsigned char*)d_in[1];
  const float* h0 = (const float*)d_in[2];
  const float* c0 = (const float*)d_in[3];
  const float* cw1 = (const float*)d_in[4];  const float* cb1 = (const float*)d_in[5];
  const float* cw2 = (const float*)d_in[6];  const float* cb2 = (const float*)d_in[7];
  const float* cw3 = (const float*)d_in[8];  const float* cb3 = (const float*)d_in[9];
  const float* cw4 = (const float*)d_in[10]; const float* cb4 = (const float*)d_in[11];
  const float* wih0 = (const float*)d_in[12]; const float* whh0 = (const float*)d_in[13];
  const float* bih0 = (const float*)d_in[14]; const float* bhh0 = (const float*)d_in[15];
  const float* wih1 = (const float*)d_in[16]; const float* whh1 = (const float*)d_in[17];
  const float* bih1 = (const float*)d_in[18]; const float* bhh1 = (const float*)d_in[19];
  const float* pw = (const float*)d_in[20]; const float* pb = (const float*)d_in[21];
  const float* bw = (const float*)d_in[22]; const float* bb = (const float*)d_in[23];

  // workspace layout (~51 MB, all f32)
  float* featT = (float*)d_ws;                      //  1,179,648  [288][4096]
  float* G0    = featT + 1179648;                   //  4,194,304
  float* G1    = G0 + 4194304;                      //  4,194,304
  float* h0aT  = G1 + 4194304;                      //  1,048,576  [256][4096]
  float* h1aT  = h0aT + 1048576;                    //  1,048,576
  float* wih0T = h1aT + 1048576;                    //    294,912
  float* wih1T = wih0T + 294912;                    //    262,144
  float* wq0   = wih1T + 262144;                    //    262,144  whh0 quad layout
  float* wq1   = wq0 + 262144;                      //    262,144  whh1 quad layout
  float* wc2   = wq1 + 262144;                      //      9,216
  float* wc3   = wc2 + 9216;
  float* wc4   = wc3 + 9216;
  float* pwT   = wc4 + 9216;                        //      4,096
  float* ndb   = pwT + 4096;                        //      4,096

  float* out = (float*)d_out;
  float* o_hT = out + 57344;
  float* o_cT = out + 90112;

  k_prep<<<4348, 256, 0, stream>>>(wih0, wih1, whh0, whh1, cw2, cw3, cw4, pw, bw,
                                   wih0T, wih1T, wq0, wq1, wc2, wc3, wc4, pwT);
  k_donecvt<<<1, 1024, 0, stream>>>(done, ndb);
  k_convall<<<4096, 512, 0, stream>>>(frame, cw1, cb1, wc2, cb2, wc3, cb3, wc4, cb4,
                                      featT);
  k_gemm2<<<1024, 256, 0, stream>>>(featT, wih0T, bih0, bhh0, G0, 288);
  k_scan<<<64, 1024, 0, stream>>>(wq0, G0, h0, c0, ndb, h0aT, o_hT, o_cT);
  k_gemm2<<<1024, 256, 0, stream>>>(h0aT, wih1T, bih1, bhh1, G1, 256);
  k_scan<<<64, 1024, 0, stream>>>(wq1, G1, h0 + 16384, c0 + 16384, ndb, h1aT,
                                  o_hT + 16384, o_cT + 16384);
  k_heads<<<16, 256, 0, stream>>>(h1aT, pwT, pb, bb, out);
}